// Round 10
// baseline (266.727 us; speedup 1.0000x reference)
//
#include <hip/hip_runtime.h>
#include <math.h>

#define NPTS 100000
#define NSAMP 16
#define NROWS (NPTS*NSAMP)
#define EPS 1e-5f

#define NQKV ((NPTS + 63)/64)
#define GRID_B 1024
#define GRID_C 2048
#define GRID_D 2048
#define GRID_E 2048

// stats layout (float offsets, relative to stats base `st`)
#define S_BN1A 0
#define S_BN1B 4
#define S_BN2A 8
#define S_BN2B 72
#define S_BN3A 136
#define S_BN3B 144
#define S_PARTB 160
#define S_PARTC (S_PARTB + GRID_B*8)
#define S_PARTD (S_PARTC + GRID_C*128)

typedef __attribute__((ext_vector_type(8))) _Float16 f16x8;
typedef __attribute__((ext_vector_type(4))) float f32x4;

__device__ __forceinline__ float bf2f(unsigned short u) {
    return __uint_as_float(((unsigned int)u) << 16);
}
// v_cvt_pk_bf16_f32: packs 2 f32 -> 2 bf16 (RNE) in one instruction
__device__ __forceinline__ unsigned int cvt_pk_bf16(float lo, float hi) {
    unsigned int r;
    asm("v_cvt_pk_bf16_f32 %0, %1, %2" : "=v"(r) : "v"(lo), "v"(hi));
    return r;
}
// uniform-lane broadcast via v_readlane (no LDS traffic)
__device__ __forceinline__ float rlF(float v, int t) {
    return __int_as_float(__builtin_amdgcn_readlane(__float_as_int(v), t));
}

// ---------------------------------------------------------------------------
// Kernel A (fused): blocks [0,NQKV) compute xqb/xkb/xvb (all bf16);
// blocks [NQKV,+GRID_B) compute BN1 partial stats.
// ---------------------------------------------------------------------------
__global__ __launch_bounds__(256) void qkv_bn1_kernel(
    const float* __restrict__ x,
    const float* __restrict__ Wq, const float* __restrict__ bq,
    const float* __restrict__ Wk, const float* __restrict__ bk,
    const float* __restrict__ Wv, const float* __restrict__ bv,
    unsigned short* __restrict__ xqb, unsigned short* __restrict__ xkb,
    unsigned short* __restrict__ xvb,
    const float* __restrict__ p, const int* __restrict__ idx,
    const float* __restrict__ Wp1, const float* __restrict__ bp1,
    float* __restrict__ part)
{
    __shared__ __align__(16) float xsh[64][68];
    __shared__ __align__(16) float wsh[64][64];
    __shared__ float red16[4][6];
    const int tid = threadIdx.x;

    if (blockIdx.x >= NQKV) {
        const int b = blockIdx.x - NQKV;
        float w9[9], bb[3];
        #pragma unroll
        for (int i = 0; i < 9; ++i) w9[i] = Wp1[i];
        #pragma unroll
        for (int i = 0; i < 3; ++i) bb[i] = bp1[i];

        float s0=0.f,s1=0.f,s2=0.f,q0=0.f,q1=0.f,q2=0.f;
        for (int row = b*256 + tid; row < NROWS; row += GRID_B*256) {
            const int n = row >> 4;
            const int j = idx[row];
            const float d0 = p[j*3+0] - p[n*3+0];
            const float d1 = p[j*3+1] - p[n*3+1];
            const float d2 = p[j*3+2] - p[n*3+2];
            const float t0 = d0*w9[0] + d1*w9[3] + d2*w9[6] + bb[0];
            const float t1 = d0*w9[1] + d1*w9[4] + d2*w9[7] + bb[1];
            const float t2 = d0*w9[2] + d1*w9[5] + d2*w9[8] + bb[2];
            s0 += t0; s1 += t1; s2 += t2;
            q0 += t0*t0; q1 += t1*t1; q2 += t2*t2;
        }
        #pragma unroll
        for (int m = 32; m >= 1; m >>= 1) {
            s0 += __shfl_xor(s0, m); s1 += __shfl_xor(s1, m); s2 += __shfl_xor(s2, m);
            q0 += __shfl_xor(q0, m); q1 += __shfl_xor(q1, m); q2 += __shfl_xor(q2, m);
        }
        const int lane = tid & 63, wid = tid >> 6;
        if (lane == 0) {
            red16[wid][0]=s0; red16[wid][1]=s1; red16[wid][2]=s2;
            red16[wid][3]=q0; red16[wid][4]=q1; red16[wid][5]=q2;
        }
        __syncthreads();
        if (tid < 6)
            part[b*8 + tid] = red16[0][tid]+red16[1][tid]+red16[2][tid]+red16[3][tid];
        return;
    }

    const int r0 = blockIdx.x * 64;
    {
        const int row = tid >> 4, c4 = tid & 15;
        #pragma unroll
        for (int rr = 0; rr < 4; ++rr) {
            const int r = row + rr*16;
            const int gr = r0 + r;
            float4 v = (gr < NPTS) ? *(const float4*)&x[(size_t)gr*64 + c4*4]
                                   : make_float4(0.f, 0.f, 0.f, 0.f);
            *(float4*)&xsh[r][c4*4] = v;
        }
    }

    const int tr = tid >> 4, tc = tid & 15;

    for (int m = 0; m < 3; ++m) {
        const float* __restrict__ W  = (m == 0) ? Wq : (m == 1) ? Wk : Wv;
        const float* __restrict__ bs = (m == 0) ? bq : (m == 1) ? bk : bv;
        unsigned short* __restrict__ dst = (m == 0) ? xqb : (m == 1) ? xkb : xvb;

        __syncthreads();
        for (int l = tid; l < 1024; l += 256)
            *(float4*)&wsh[l >> 4][(l & 15)*4] = *(const float4*)&W[l*4];
        __syncthreads();

        float acc[4][4];
        {
            const float4 b4 = *(const float4*)&bs[tc*4];
            #pragma unroll
            for (int rr = 0; rr < 4; ++rr) {
                acc[rr][0] = b4.x; acc[rr][1] = b4.y;
                acc[rr][2] = b4.z; acc[rr][3] = b4.w;
            }
        }

        #pragma unroll 4
        for (int k4 = 0; k4 < 16; ++k4) {
            float4 xr[4];
            #pragma unroll
            for (int rr = 0; rr < 4; ++rr)
                xr[rr] = *(const float4*)&xsh[tr + 16*rr][k4*4];
            float4 wr[4];
            #pragma unroll
            for (int kk = 0; kk < 4; ++kk)
                wr[kk] = *(const float4*)&wsh[k4*4 + kk][tc*4];
            #pragma unroll
            for (int rr = 0; rr < 4; ++rr) {
                acc[rr][0] += xr[rr].x*wr[0].x + xr[rr].y*wr[1].x + xr[rr].z*wr[2].x + xr[rr].w*wr[3].x;
                acc[rr][1] += xr[rr].x*wr[0].y + xr[rr].y*wr[1].y + xr[rr].z*wr[2].y + xr[rr].w*wr[3].y;
                acc[rr][2] += xr[rr].x*wr[0].z + xr[rr].y*wr[1].z + xr[rr].z*wr[2].z + xr[rr].w*wr[3].z;
                acc[rr][3] += xr[rr].x*wr[0].w + xr[rr].y*wr[1].w + xr[rr].z*wr[2].w + xr[rr].w*wr[3].w;
            }
        }

        #pragma unroll
        for (int rr = 0; rr < 4; ++rr) {
            const int gr = r0 + tr + 16*rr;
            if (gr < NPTS) {
                uint2 o;
                o.x = cvt_pk_bf16(acc[rr][0], acc[rr][1]);
                o.y = cvt_pk_bf16(acc[rr][2], acc[rr][3]);
                *(uint2*)&dst[(size_t)gr*64 + tc*4] = o;
            }
        }
    }
}

// ---------------------------------------------------------------------------
// BN finalize
// ---------------------------------------------------------------------------
__global__ __launch_bounds__(256) void bn_fin_kernel(
    const float* __restrict__ part, int nblk, int stride, int nch,
    const float* __restrict__ g, const float* __restrict__ beta,
    float* __restrict__ aout, float* __restrict__ bout)
{
    const int c = blockIdx.x;
    const int tid = threadIdx.x;
    float s = 0.f, q = 0.f;
    for (int b = tid; b < nblk; b += 256) {
        s += part[(size_t)b*stride + c];
        q += part[(size_t)b*stride + nch + c];
    }
    #pragma unroll
    for (int m = 32; m >= 1; m >>= 1) { s += __shfl_xor(s, m); q += __shfl_xor(q, m); }
    __shared__ float rs[4], rq[4];
    if ((tid & 63) == 0) { rs[tid >> 6] = s; rq[tid >> 6] = q; }
    __syncthreads();
    if (tid == 0) {
        s = rs[0]+rs[1]+rs[2]+rs[3];
        q = rq[0]+rq[1]+rq[2]+rq[3];
        const float inv = 1.0f / (float)NROWS;
        const float mean = s * inv;
        const float var = fmaxf(q * inv - mean*mean, 0.f);
        const float a = g[c] * rsqrtf(var + EPS);
        aout[c] = a;
        bout[c] = beta[c] - a * mean;
    }
}

// ---------------------------------------------------------------------------
// Kernel C: BN2 stats. 2-deep software pipeline: next point's idx/xq/p loads
// issue before current point's 16-gather body.
// ---------------------------------------------------------------------------
__global__ __launch_bounds__(256, 8) void bn2_stats_kernel(
    const float* __restrict__ p, const int* __restrict__ idx,
    const unsigned short* __restrict__ xqb, const unsigned short* __restrict__ xkb,
    const float* __restrict__ Wp1, const float* __restrict__ bp1,
    const float* __restrict__ Wp2, const float* __restrict__ bp2,
    const float* __restrict__ st, float* __restrict__ part)
{
    const int tid = threadIdx.x, lane = tid & 63, wid = tid >> 6;
    float w9[9], bb[3], a1[3], b1[3];
    #pragma unroll
    for (int i = 0; i < 9; ++i) w9[i] = Wp1[i];
    #pragma unroll
    for (int i = 0; i < 3; ++i) { bb[i] = bp1[i]; a1[i] = st[S_BN1A+i]; b1[i] = st[S_BN1B+i]; }
    const float wc0 = Wp2[lane], wc1 = Wp2[64+lane], wc2 = Wp2[128+lane], bpc = bp2[lane];
    const int lane16 = lane & 15;
    const int nw = gridDim.x * 4;

    float s = 0.f, q = 0.f;
    int pt = blockIdx.x*4 + wid;
    int jn = 0; float xqn = 0.f, pn0 = 0.f, pn1 = 0.f, pn2 = 0.f;
    float pj0 = 0.f, pj1 = 0.f, pj2 = 0.f;
    if (pt < NPTS) {
        jn = idx[pt*16 + lane16];
        xqn = bf2f(xqb[(size_t)pt*64 + lane]);
        pn0 = p[pt*3]; pn1 = p[pt*3+1]; pn2 = p[pt*3+2];
        pj0 = p[jn*3]; pj1 = p[jn*3+1]; pj2 = p[jn*3+2];
    }
    while (pt < NPTS) {
        const int jreg = jn;
        const float xqc = xqn;
        const float d0 = pj0 - pn0, d1 = pj1 - pn1, d2 = pj2 - pn2;
        const int ptn = pt + nw;
        if (ptn < NPTS) {   // prefetch next point
            jn = idx[ptn*16 + lane16];
            xqn = bf2f(xqb[(size_t)ptn*64 + lane]);
            pn0 = p[ptn*3]; pn1 = p[ptn*3+1]; pn2 = p[ptn*3+2];
            pj0 = p[jn*3]; pj1 = p[jn*3+1]; pj2 = p[jn*3+2];
        }
        const float t0 = d0*w9[0] + d1*w9[3] + d2*w9[6] + bb[0];
        const float t1 = d0*w9[1] + d1*w9[4] + d2*w9[7] + bb[1];
        const float t2 = d0*w9[2] + d1*w9[5] + d2*w9[8] + bb[2];
        const float h0 = fmaxf(a1[0]*t0 + b1[0], 0.f);
        const float h1 = fmaxf(a1[1]*t1 + b1[1], 0.f);
        const float h2 = fmaxf(a1[2]*t2 + b1[2], 0.f);

        #pragma unroll
        for (int t = 0; t < 16; ++t) {
            const int jt = __builtin_amdgcn_readlane(jreg, t);
            const float g0 = rlF(h0, t), g1 = rlF(h1, t), g2 = rlF(h2, t);
            const float pr = fmaf(g0, wc0, fmaf(g1, wc1, fmaf(g2, wc2, bpc)));
            const float r = bf2f(xkb[(size_t)jt*64 + lane]) - xqc + pr;
            s += r; q = fmaf(r, r, q);
        }
        pt = ptn;
    }
    __shared__ float redS[4][64], redQ[4][64];
    redS[wid][lane] = s; redQ[wid][lane] = q;
    __syncthreads();
    if (tid < 64) {
        const float S = redS[0][tid]+redS[1][tid]+redS[2][tid]+redS[3][tid];
        const float Q = redQ[0][tid]+redQ[1][tid]+redQ[2][tid]+redQ[3][tid];
        part[(size_t)blockIdx.x*128 + tid] = S;
        part[(size_t)blockIdx.x*128 + 64 + tid] = Q;
    }
}

// ---------------------------------------------------------------------------
// Kernel D: w1 = relu(bn2(r_qk)) @ Ww1 + bww1 -> bf16 [NROWS,8] + BN3 stats.
// H staged f16 in XOR-swizzled LDS rows; 2x v_mfma_f32_16x16x32_f16.
// 2-deep prefetch pipeline like bn2.
// ---------------------------------------------------------------------------
__global__ __launch_bounds__(256, 8) void w1_kernel(
    const float* __restrict__ p, const int* __restrict__ idx,
    const unsigned short* __restrict__ xqb, const unsigned short* __restrict__ xkb,
    const float* __restrict__ Wp1, const float* __restrict__ bp1,
    const float* __restrict__ Wp2, const float* __restrict__ bp2,
    const float* __restrict__ Ww1, const float* __restrict__ bww1,
    const float* __restrict__ st, unsigned short* __restrict__ w1out,
    float* __restrict__ part)
{
    __shared__ __align__(16) _Float16 hl[4][16][64];   // f16 H rows, XOR-swizzled
    const int tid = threadIdx.x, lane = tid & 63, wid = tid >> 6;

    float w9[9], bb[3], a1[3], b1[3];
    #pragma unroll
    for (int i = 0; i < 9; ++i) w9[i] = Wp1[i];
    #pragma unroll
    for (int i = 0; i < 3; ++i) { bb[i] = bp1[i]; a1[i] = st[S_BN1A+i]; b1[i] = st[S_BN1B+i]; }

    const int c = lane;
    const float wc0 = Wp2[c], wc1 = Wp2[64+c], wc2 = Wp2[128+c], bpc = bp2[c];
    const float a2c = st[S_BN2A + c], b2c = st[S_BN2B + c];
    const int lane16 = lane & 15;
    const int kgrp = lane >> 4;            // 0..3

    // A fragments: A[m][k] = Ww1[k][m], m = lane&15 (rows 8..15 zero)
    f16x8 aF0, aF1;
    {
        const int m = lane16;
        #pragma unroll
        for (int i = 0; i < 8; ++i) {
            const int k0 = kgrp*4 + (i & 3) + 16*(i >> 2);
            const int i0 = (m < 8) ? (k0*8 + m) : 0;
            const int i1 = (m < 8) ? ((k0 + 32)*8 + m) : 0;
            aF0[i] = (m < 8) ? (_Float16)Ww1[i0] : (_Float16)0.f;
            aF1[i] = (m < 8) ? (_Float16)Ww1[i1] : (_Float16)0.f;
        }
    }
    f32x4 cb;
    #pragma unroll
    for (int r = 0; r < 4; ++r) cb[r] = bww1[(kgrp*4 + r) & 7];

    float s3[4] = {0.f,0.f,0.f,0.f}, q3[4] = {0.f,0.f,0.f,0.f};
    const int nw = gridDim.x * 4;
    int pt = blockIdx.x*4 + wid;
    int jn = 0; float xqn = 0.f, pn0 = 0.f, pn1 = 0.f, pn2 = 0.f;
    float pj0 = 0.f, pj1 = 0.f, pj2 = 0.f;
    if (pt < NPTS) {
        jn = idx[pt*16 + lane16];
        xqn = bf2f(xqb[(size_t)pt*64 + lane]);
        pn0 = p[pt*3]; pn1 = p[pt*3+1]; pn2 = p[pt*3+2];
        pj0 = p[jn*3]; pj1 = p[jn*3+1]; pj2 = p[jn*3+2];
    }
    while (pt < NPTS) {
        const int jreg = jn;
        const float xqc = xqn;
        const float d0 = pj0 - pn0, d1 = pj1 - pn1, d2 = pj2 - pn2;
        const int ptn = pt + nw;
        if (ptn < NPTS) {   // prefetch next point
            jn = idx[ptn*16 + lane16];
            xqn = bf2f(xqb[(size_t)ptn*64 + lane]);
            pn0 = p[ptn*3]; pn1 = p[ptn*3+1]; pn2 = p[ptn*3+2];
            pj0 = p[jn*3]; pj1 = p[jn*3+1]; pj2 = p[jn*3+2];
        }
        const float t0v = d0*w9[0] + d1*w9[3] + d2*w9[6] + bb[0];
        const float t1v = d0*w9[1] + d1*w9[4] + d2*w9[7] + bb[1];
        const float t2v = d0*w9[2] + d1*w9[5] + d2*w9[8] + bb[2];
        const float h0 = fmaxf(a1[0]*t0v + b1[0], 0.f);
        const float h1 = fmaxf(a1[1]*t1v + b1[1], 0.f);
        const float h2 = fmaxf(a1[2]*t2v + b1[2], 0.f);

        #pragma unroll
        for (int t = 0; t < 16; ++t) {
            const int jt = __builtin_amdgcn_readlane(jreg, t);
            const float g0 = rlF(h0, t), g1 = rlF(h1, t), g2 = rlF(h2, t);
            const float pr = fmaf(g0, wc0, fmaf(g1, wc1, fmaf(g2, wc2, bpc)));
            const float r = bf2f(xkb[(size_t)jt*64 + lane]) - xqc + pr;
            hl[wid][t][lane ^ ((t & 7) << 3)] = (_Float16)fmaxf(fmaf(a2c, r, b2c), 0.f);
        }

        const int t = lane16;
        const int key = (t & 7) << 3;
        union { f16x8 v; uint2 u[2]; } b0u, b1u;
        b0u.u[0] = *(const uint2*)&hl[wid][t][(kgrp*4)      ^ key];
        b0u.u[1] = *(const uint2*)&hl[wid][t][(kgrp*4 + 16) ^ key];
        b1u.u[0] = *(const uint2*)&hl[wid][t][(kgrp*4 + 32) ^ key];
        b1u.u[1] = *(const uint2*)&hl[wid][t][(kgrp*4 + 48) ^ key];

        f32x4 acc = __builtin_amdgcn_mfma_f32_16x16x32_f16(aF0, b0u.v, cb, 0, 0, 0);
        acc = __builtin_amdgcn_mfma_f32_16x16x32_f16(aF1, b1u.v, acc, 0, 0, 0);

        // D: col = lane&15 = t, row = kgrp*4 + r = j (lanes < 32 hold j = 0..7)
        if (lane < 32) {
            uint2 o;
            o.x = cvt_pk_bf16(acc[0], acc[1]);
            o.y = cvt_pk_bf16(acc[2], acc[3]);
            *(uint2*)&w1out[(size_t)pt*128 + lane16*8 + kgrp*4] = o;
            #pragma unroll
            for (int r = 0; r < 4; ++r) {
                s3[r] += acc[r];
                q3[r] = fmaf(acc[r], acc[r], q3[r]);
            }
        }
        pt = ptn;
    }

    #pragma unroll
    for (int m = 8; m >= 1; m >>= 1) {
        #pragma unroll
        for (int r = 0; r < 4; ++r) {
            s3[r] += __shfl_xor(s3[r], m);
            q3[r] += __shfl_xor(q3[r], m);
        }
    }
    __shared__ float redS[4][8], redQ[4][8];
    if (lane == 0 || lane == 16) {
        const int jb = (lane >> 4) * 4;
        #pragma unroll
        for (int r = 0; r < 4; ++r) { redS[wid][jb+r] = s3[r]; redQ[wid][jb+r] = q3[r]; }
    }
    __syncthreads();
    if (tid < 8) {
        const float S = redS[0][tid]+redS[1][tid]+redS[2][tid]+redS[3][tid];
        const float Q = redQ[0][tid]+redQ[1][tid]+redQ[2][tid]+redQ[3][tid];
        part[(size_t)blockIdx.x*16 + tid]     = S;
        part[(size_t)blockIdx.x*16 + 8 + tid] = Q;
    }
}

// ---------------------------------------------------------------------------
// Kernel E: w2 = relu(bn3(w1)) @ Ww2 + bww2; softmax (no max-sub — inputs
// bounded by BN3+relu scale); weighted sum. 2-deep prefetch pipeline.
// ---------------------------------------------------------------------------
__global__ __launch_bounds__(256, 8) void out_kernel(
    const float* __restrict__ p, const int* __restrict__ idx,
    const unsigned short* __restrict__ xvb, const unsigned short* __restrict__ w1b,
    const float* __restrict__ Wp1, const float* __restrict__ bp1,
    const float* __restrict__ Wp2, const float* __restrict__ bp2,
    const float* __restrict__ Ww2, const float* __restrict__ bww2,
    const float* __restrict__ st, float* __restrict__ out)
{
    __shared__ float wl[4][16][8];
    const int tid = threadIdx.x, lane = tid & 63, wid = tid >> 6;
    const int j8 = lane & 7, t0 = lane >> 3;
    const int lane16 = lane & 15;

    float w9[9], bb[3], a1[3], b1[3];
    #pragma unroll
    for (int i = 0; i < 9; ++i) w9[i] = Wp1[i];
    #pragma unroll
    for (int i = 0; i < 3; ++i) { bb[i] = bp1[i]; a1[i] = st[S_BN1A+i]; b1[i] = st[S_BN1B+i]; }
    float ww2c[8];
    #pragma unroll
    for (int i = 0; i < 8; ++i) ww2c[i] = Ww2[i*8 + j8];
    const float a3j = st[S_BN3A + j8], b3j = st[S_BN3B + j8];
    const float bw2j = bww2[j8];
    const int c = lane;
    const float wc0 = Wp2[c], wc1 = Wp2[64+c], wc2 = Wp2[128+c], bpc = bp2[c];

    const int nw = gridDim.x * 4;
    int pt = blockIdx.x*4 + wid;
    int jn = 0; float pn0 = 0.f, pn1 = 0.f, pn2 = 0.f;
    float pj0 = 0.f, pj1 = 0.f, pj2 = 0.f, v0n = 0.f, v1n = 0.f;
    if (pt < NPTS) {
        jn = idx[pt*16 + lane16];
        pn0 = p[pt*3]; pn1 = p[pt*3+1]; pn2 = p[pt*3+2];
        pj0 = p[jn*3]; pj1 = p[jn*3+1]; pj2 = p[jn*3+2];
        v0n = bf2f(w1b[(size_t)pt*128 + lane]);
        v1n = bf2f(w1b[(size_t)pt*128 + 64 + lane]);
    }
    while (pt < NPTS) {
        const int jreg = jn;
        const float d0 = pj0 - pn0, d1 = pj1 - pn1, d2 = pj2 - pn2;
        const float val0 = v0n, val1 = v1n;
        const int ptn = pt + nw;
        if (ptn < NPTS) {   // prefetch next point
            jn = idx[ptn*16 + lane16];
            pn0 = p[ptn*3]; pn1 = p[ptn*3+1]; pn2 = p[ptn*3+2];
            pj0 = p[jn*3]; pj1 = p[jn*3+1]; pj2 = p[jn*3+2];
            v0n = bf2f(w1b[(size_t)ptn*128 + lane]);
            v1n = bf2f(w1b[(size_t)ptn*128 + 64 + lane]);
        }
        const float t1v = d0*w9[0] + d1*w9[3] + d2*w9[6] + bb[0];
        const float t2v = d0*w9[1] + d1*w9[4] + d2*w9[7] + bb[1];
        const float t3v = d0*w9[2] + d1*w9[5] + d2*w9[8] + bb[2];
        const float h0 = fmaxf(a1[0]*t1v + b1[0], 0.f);
        const float h1 = fmaxf(a1[1]*t2v + b1[1], 0.f);
        const float h2 = fmaxf(a1[2]*t3v + b1[2], 0.f);

        // phase 1: bn3 + 8x8 matmul within 8-lane groups; softmax over t
        const float r0 = fmaxf(a3j*val0 + b3j, 0.f);
        const float r1 = fmaxf(a3j*val1 + b3j, 0.f);
        float v0 = bw2j, v1 = bw2j;
        const int gbase = lane & 56;
        #pragma unroll
        for (int jj = 0; jj < 8; ++jj) {
            v0 += __shfl(r0, gbase + jj) * ww2c[jj];
            v1 += __shfl(r1, gbase + jj) * ww2c[jj];
        }
        float e0 = __expf(v0), e1 = __expf(v1);
        float ssum = e0 + e1;
        ssum += __shfl_xor(ssum, 8);
        ssum += __shfl_xor(ssum, 16);
        ssum += __shfl_xor(ssum, 32);
        const float inv = 1.0f / ssum;
        wl[wid][t0][j8]     = e0 * inv;
        wl[wid][t0 + 8][j8] = e1 * inv;

        // phase 2: weighted sum over neighbors, lane = output channel
        float acc = 0.f;
        #pragma unroll
        for (int t = 0; t < 16; ++t) {
            const int jt = __builtin_amdgcn_readlane(jreg, t);
            const float g0 = rlF(h0, t), g1 = rlF(h1, t), g2 = rlF(h2, t);
            const float pr = fmaf(g0, wc0, fmaf(g1, wc1, fmaf(g2, wc2, bpc)));
            const float wt = wl[wid][t][j8];
            acc = fmaf(bf2f(xvb[(size_t)jt*64 + c]) + pr, wt, acc);
        }
        out[(size_t)pt*64 + c] = acc;
        pt = ptn;
    }
}

// ---------------------------------------------------------------------------
extern "C" void kernel_launch(void* const* d_in, const int* in_sizes, int n_in,
                              void* d_out, int out_size, void* d_ws, size_t ws_size,
                              hipStream_t stream)
{
    const float* p    = (const float*)d_in[0];
    const float* x    = (const float*)d_in[1];
    const int*   idx  = (const int*)d_in[3];
    const float* Wq   = (const float*)d_in[4];
    const float* bq   = (const float*)d_in[5];
    const float* Wk   = (const float*)d_in[6];
    const float* bk   = (const float*)d_in[7];
    const float* Wv   = (const float*)d_in[8];
    const float* bv   = (const float*)d_in[9];
    const float* Wp1  = (const float*)d_in[10];
    const float* bp1  = (const float*)d_in[11];
    const float* gp   = (const float*)d_in[12];
    const float* betap= (const float*)d_in[13];
    const float* Wp2  = (const float*)d_in[14];
    const float* bp2  = (const float*)d_in[15];
    const float* gw1  = (const float*)d_in[16];
    const float* bw1  = (const float*)d_in[17];
    const float* Ww1  = (const float*)d_in[18];
    const float* bww1 = (const float*)d_in[19];
    const float* gw2  = (const float*)d_in[20];
    const float* bw2  = (const float*)d_in[21];
    const float* Ww2  = (const float*)d_in[22];
    const float* bww2 = (const float*)d_in[23];

    float* out = (float*)d_out;
    float* ws  = (float*)d_ws;

    // workspace (float offsets): xqb bf16 [N*32 fl] | xkb bf16 [N*32] |
    // xvb bf16 [N*32] | w1b bf16 [N*64] | stats
    unsigned short* xqb = (unsigned short*)ws;
    unsigned short* xkb = (unsigned short*)(ws + (size_t)NPTS*32);
    unsigned short* xvb = (unsigned short*)(ws + (size_t)NPTS*64);
    unsigned short* w1b = (unsigned short*)(ws + (size_t)NPTS*96);
    float*          st  = ws + (size_t)NPTS*160;

    qkv_bn1_kernel<<<NQKV + GRID_B, 256, 0, stream>>>(
        x, Wq, bq, Wk, bk, Wv, bv, xqb, xkb, xvb,
        p, idx, Wp1, bp1, st + S_PARTB);
    bn_fin_kernel<<<3, 256, 0, stream>>>(st + S_PARTB, GRID_B, 8, 3, gp, betap,
                                         st + S_BN1A, st + S_BN1B);

    bn2_stats_kernel<<<GRID_C, 256, 0, stream>>>(p, idx, xqb, xkb, Wp1, bp1, Wp2, bp2,
                                                 st, st + S_PARTC);
    bn_fin_kernel<<<64, 256, 0, stream>>>(st + S_PARTC, GRID_C, 128, 64, gw1, bw1,
                                          st + S_BN2A, st + S_BN2B);

    w1_kernel<<<GRID_D, 256, 0, stream>>>(p, idx, xqb, xkb, Wp1, bp1, Wp2, bp2,
                                          Ww1, bww1, st, w1b, st + S_PARTD);
    bn_fin_kernel<<<8, 256, 0, stream>>>(st + S_PARTD, GRID_D, 16, 8, gw2, bw2,
                                         st + S_BN3A, st + S_BN3B);

    out_kernel<<<GRID_E, 256, 0, stream>>>(p, idx, xvb, w1b, Wp1, bp1, Wp2, bp2,
                                           Ww2, bww2, st, out);
}

// Round 11
// 252.776 us; speedup vs baseline: 1.0552x; 1.0552x over previous
//
#include <hip/hip_runtime.h>
#include <math.h>

#define NPTS 100000
#define NSAMP 16
#define NROWS (NPTS*NSAMP)
#define EPS 1e-5f

#define NQKV ((NPTS + 63)/64)
#define GRID_B 1024
#define GRID_C 2048
#define GRID_D 2048
#define GRID_E 2048

// stats layout (float offsets, relative to stats base `st`)
#define S_BN1A 0
#define S_BN1B 4
#define S_BN2A 8
#define S_BN2B 72
#define S_BN3A 136
#define S_BN3B 144
#define S_PARTB 160
#define S_PARTC (S_PARTB + GRID_B*8)
#define S_PARTD (S_PARTC + GRID_C*128)

typedef __attribute__((ext_vector_type(8))) _Float16 f16x8;
typedef __attribute__((ext_vector_type(4))) float f32x4;

__device__ __forceinline__ float bf2f(unsigned short u) {
    return __uint_as_float(((unsigned int)u) << 16);
}
// v_cvt_pk_bf16_f32: packs 2 f32 -> 2 bf16 (RNE) in one instruction
__device__ __forceinline__ unsigned int cvt_pk_bf16(float lo, float hi) {
    unsigned int r;
    asm("v_cvt_pk_bf16_f32 %0, %1, %2" : "=v"(r) : "v"(lo), "v"(hi));
    return r;
}
// uniform-lane broadcast via v_readlane (no LDS traffic)
__device__ __forceinline__ float rlF(float v, int t) {
    return __int_as_float(__builtin_amdgcn_readlane(__float_as_int(v), t));
}

// ---------------------------------------------------------------------------
// Kernel A (fused): blocks [0,NQKV) compute xq (f32) / xkb / xvb (bf16);
// blocks [NQKV,+GRID_B) compute BN1 partial stats.
// ---------------------------------------------------------------------------
__global__ __launch_bounds__(256) void qkv_bn1_kernel(
    const float* __restrict__ x,
    const float* __restrict__ Wq, const float* __restrict__ bq,
    const float* __restrict__ Wk, const float* __restrict__ bk,
    const float* __restrict__ Wv, const float* __restrict__ bv,
    float* __restrict__ xq, unsigned short* __restrict__ xkb,
    unsigned short* __restrict__ xvb,
    const float* __restrict__ p, const int* __restrict__ idx,
    const float* __restrict__ Wp1, const float* __restrict__ bp1,
    float* __restrict__ part)
{
    __shared__ __align__(16) float xsh[64][68];
    __shared__ __align__(16) float wsh[64][64];
    __shared__ float red16[4][6];
    const int tid = threadIdx.x;

    if (blockIdx.x >= NQKV) {
        const int b = blockIdx.x - NQKV;
        float w9[9], bb[3];
        #pragma unroll
        for (int i = 0; i < 9; ++i) w9[i] = Wp1[i];
        #pragma unroll
        for (int i = 0; i < 3; ++i) bb[i] = bp1[i];

        float s0=0.f,s1=0.f,s2=0.f,q0=0.f,q1=0.f,q2=0.f;
        for (int row = b*256 + tid; row < NROWS; row += GRID_B*256) {
            const int n = row >> 4;
            const int j = idx[row];
            const float d0 = p[j*3+0] - p[n*3+0];
            const float d1 = p[j*3+1] - p[n*3+1];
            const float d2 = p[j*3+2] - p[n*3+2];
            const float t0 = d0*w9[0] + d1*w9[3] + d2*w9[6] + bb[0];
            const float t1 = d0*w9[1] + d1*w9[4] + d2*w9[7] + bb[1];
            const float t2 = d0*w9[2] + d1*w9[5] + d2*w9[8] + bb[2];
            s0 += t0; s1 += t1; s2 += t2;
            q0 += t0*t0; q1 += t1*t1; q2 += t2*t2;
        }
        #pragma unroll
        for (int m = 32; m >= 1; m >>= 1) {
            s0 += __shfl_xor(s0, m); s1 += __shfl_xor(s1, m); s2 += __shfl_xor(s2, m);
            q0 += __shfl_xor(q0, m); q1 += __shfl_xor(q1, m); q2 += __shfl_xor(q2, m);
        }
        const int lane = tid & 63, wid = tid >> 6;
        if (lane == 0) {
            red16[wid][0]=s0; red16[wid][1]=s1; red16[wid][2]=s2;
            red16[wid][3]=q0; red16[wid][4]=q1; red16[wid][5]=q2;
        }
        __syncthreads();
        if (tid < 6)
            part[b*8 + tid] = red16[0][tid]+red16[1][tid]+red16[2][tid]+red16[3][tid];
        return;
    }

    const int r0 = blockIdx.x * 64;
    {
        const int row = tid >> 4, c4 = tid & 15;
        #pragma unroll
        for (int rr = 0; rr < 4; ++rr) {
            const int r = row + rr*16;
            const int gr = r0 + r;
            float4 v = (gr < NPTS) ? *(const float4*)&x[(size_t)gr*64 + c4*4]
                                   : make_float4(0.f, 0.f, 0.f, 0.f);
            *(float4*)&xsh[r][c4*4] = v;
        }
    }

    const int tr = tid >> 4, tc = tid & 15;

    for (int m = 0; m < 3; ++m) {
        const float* __restrict__ W  = (m == 0) ? Wq : (m == 1) ? Wk : Wv;
        const float* __restrict__ bs = (m == 0) ? bq : (m == 1) ? bk : bv;

        __syncthreads();
        for (int l = tid; l < 1024; l += 256)
            *(float4*)&wsh[l >> 4][(l & 15)*4] = *(const float4*)&W[l*4];
        __syncthreads();

        float acc[4][4];
        {
            const float4 b4 = *(const float4*)&bs[tc*4];
            #pragma unroll
            for (int rr = 0; rr < 4; ++rr) {
                acc[rr][0] = b4.x; acc[rr][1] = b4.y;
                acc[rr][2] = b4.z; acc[rr][3] = b4.w;
            }
        }

        #pragma unroll 4
        for (int k4 = 0; k4 < 16; ++k4) {
            float4 xr[4];
            #pragma unroll
            for (int rr = 0; rr < 4; ++rr)
                xr[rr] = *(const float4*)&xsh[tr + 16*rr][k4*4];
            float4 wr[4];
            #pragma unroll
            for (int kk = 0; kk < 4; ++kk)
                wr[kk] = *(const float4*)&wsh[k4*4 + kk][tc*4];
            #pragma unroll
            for (int rr = 0; rr < 4; ++rr) {
                acc[rr][0] += xr[rr].x*wr[0].x + xr[rr].y*wr[1].x + xr[rr].z*wr[2].x + xr[rr].w*wr[3].x;
                acc[rr][1] += xr[rr].x*wr[0].y + xr[rr].y*wr[1].y + xr[rr].z*wr[2].y + xr[rr].w*wr[3].y;
                acc[rr][2] += xr[rr].x*wr[0].z + xr[rr].y*wr[1].z + xr[rr].z*wr[2].z + xr[rr].w*wr[3].z;
                acc[rr][3] += xr[rr].x*wr[0].w + xr[rr].y*wr[1].w + xr[rr].z*wr[2].w + xr[rr].w*wr[3].w;
            }
        }

        #pragma unroll
        for (int rr = 0; rr < 4; ++rr) {
            const int gr = r0 + tr + 16*rr;
            if (gr < NPTS) {
                if (m == 0) {
                    float4 o;
                    o.x = acc[rr][0]; o.y = acc[rr][1]; o.z = acc[rr][2]; o.w = acc[rr][3];
                    *(float4*)&xq[(size_t)gr*64 + tc*4] = o;
                } else {
                    unsigned short* dst = (m == 1) ? xkb : xvb;
                    uint2 o;
                    o.x = cvt_pk_bf16(acc[rr][0], acc[rr][1]);
                    o.y = cvt_pk_bf16(acc[rr][2], acc[rr][3]);
                    *(uint2*)&dst[(size_t)gr*64 + tc*4] = o;
                }
            }
        }
    }
}

// ---------------------------------------------------------------------------
// BN finalize
// ---------------------------------------------------------------------------
__global__ __launch_bounds__(256) void bn_fin_kernel(
    const float* __restrict__ part, int nblk, int stride, int nch,
    const float* __restrict__ g, const float* __restrict__ beta,
    float* __restrict__ aout, float* __restrict__ bout)
{
    const int c = blockIdx.x;
    const int tid = threadIdx.x;
    float s = 0.f, q = 0.f;
    for (int b = tid; b < nblk; b += 256) {
        s += part[(size_t)b*stride + c];
        q += part[(size_t)b*stride + nch + c];
    }
    #pragma unroll
    for (int m = 32; m >= 1; m >>= 1) { s += __shfl_xor(s, m); q += __shfl_xor(q, m); }
    __shared__ float rs[4], rq[4];
    if ((tid & 63) == 0) { rs[tid >> 6] = s; rq[tid >> 6] = q; }
    __syncthreads();
    if (tid == 0) {
        s = rs[0]+rs[1]+rs[2]+rs[3];
        q = rq[0]+rq[1]+rq[2]+rq[3];
        const float inv = 1.0f / (float)NROWS;
        const float mean = s * inv;
        const float var = fmaxf(q * inv - mean*mean, 0.f);
        const float a = g[c] * rsqrtf(var + EPS);
        aout[c] = a;
        bout[c] = beta[c] - a * mean;
    }
}

// ---------------------------------------------------------------------------
// Kernel C: BN2 stats. Trunk computed by all lanes at lane&15; broadcast
// per-t via v_readlane. No prefetch pipeline (round-10 regression).
// ---------------------------------------------------------------------------
__global__ __launch_bounds__(256, 8) void bn2_stats_kernel(
    const float* __restrict__ p, const int* __restrict__ idx,
    const float* __restrict__ xq, const unsigned short* __restrict__ xkb,
    const float* __restrict__ Wp1, const float* __restrict__ bp1,
    const float* __restrict__ Wp2, const float* __restrict__ bp2,
    const float* __restrict__ st, float* __restrict__ part)
{
    const int tid = threadIdx.x, lane = tid & 63, wid = tid >> 6;
    float w9[9], bb[3], a1[3], b1[3];
    #pragma unroll
    for (int i = 0; i < 9; ++i) w9[i] = Wp1[i];
    #pragma unroll
    for (int i = 0; i < 3; ++i) { bb[i] = bp1[i]; a1[i] = st[S_BN1A+i]; b1[i] = st[S_BN1B+i]; }
    const float wc0 = Wp2[lane], wc1 = Wp2[64+lane], wc2 = Wp2[128+lane], bpc = bp2[lane];
    const int lane16 = lane & 15;

    float s = 0.f, q = 0.f;
    const int nw = gridDim.x * 4;
    for (int pt = blockIdx.x*4 + wid; pt < NPTS; pt += nw) {
        const float xqc = xq[(size_t)pt*64 + lane];
        const int jreg = idx[pt*16 + lane16];
        const float pn0 = p[pt*3], pn1 = p[pt*3+1], pn2 = p[pt*3+2];
        const float d0 = p[jreg*3] - pn0, d1 = p[jreg*3+1] - pn1, d2 = p[jreg*3+2] - pn2;
        const float t0 = d0*w9[0] + d1*w9[3] + d2*w9[6] + bb[0];
        const float t1 = d0*w9[1] + d1*w9[4] + d2*w9[7] + bb[1];
        const float t2 = d0*w9[2] + d1*w9[5] + d2*w9[8] + bb[2];
        const float h0 = fmaxf(a1[0]*t0 + b1[0], 0.f);
        const float h1 = fmaxf(a1[1]*t1 + b1[1], 0.f);
        const float h2 = fmaxf(a1[2]*t2 + b1[2], 0.f);

        #pragma unroll
        for (int t = 0; t < 16; ++t) {
            const int jt = __builtin_amdgcn_readlane(jreg, t);
            const float g0 = rlF(h0, t), g1 = rlF(h1, t), g2 = rlF(h2, t);
            const float pr = fmaf(g0, wc0, fmaf(g1, wc1, fmaf(g2, wc2, bpc)));
            const float r = bf2f(xkb[(size_t)jt*64 + lane]) - xqc + pr;
            s += r; q = fmaf(r, r, q);
        }
    }
    __shared__ float redS[4][64], redQ[4][64];
    redS[wid][lane] = s; redQ[wid][lane] = q;
    __syncthreads();
    if (tid < 64) {
        const float S = redS[0][tid]+redS[1][tid]+redS[2][tid]+redS[3][tid];
        const float Q = redQ[0][tid]+redQ[1][tid]+redQ[2][tid]+redQ[3][tid];
        part[(size_t)blockIdx.x*128 + tid] = S;
        part[(size_t)blockIdx.x*128 + 64 + tid] = Q;
    }
}

// ---------------------------------------------------------------------------
// Kernel D: w1 = relu(bn2(r_qk)) @ Ww1 + bww1 -> bf16 [NROWS,8] + BN3 stats.
// H staged f16 in XOR-swizzled LDS rows; 2x v_mfma_f32_16x16x32_f16
// (A = Ww1^T in registers rows 8..15 zero; B = H^T; C = bias). No prefetch.
// ---------------------------------------------------------------------------
__global__ __launch_bounds__(256, 8) void w1_kernel(
    const float* __restrict__ p, const int* __restrict__ idx,
    const float* __restrict__ xq, const unsigned short* __restrict__ xkb,
    const float* __restrict__ Wp1, const float* __restrict__ bp1,
    const float* __restrict__ Wp2, const float* __restrict__ bp2,
    const float* __restrict__ Ww1, const float* __restrict__ bww1,
    const float* __restrict__ st, unsigned short* __restrict__ w1out,
    float* __restrict__ part)
{
    __shared__ __align__(16) _Float16 hl[4][16][64];   // f16 H rows, XOR-swizzled
    const int tid = threadIdx.x, lane = tid & 63, wid = tid >> 6;

    float w9[9], bb[3], a1[3], b1[3];
    #pragma unroll
    for (int i = 0; i < 9; ++i) w9[i] = Wp1[i];
    #pragma unroll
    for (int i = 0; i < 3; ++i) { bb[i] = bp1[i]; a1[i] = st[S_BN1A+i]; b1[i] = st[S_BN1B+i]; }

    const int c = lane;
    const float wc0 = Wp2[c], wc1 = Wp2[64+c], wc2 = Wp2[128+c], bpc = bp2[c];
    const float a2c = st[S_BN2A + c], b2c = st[S_BN2B + c];
    const int lane16 = lane & 15;
    const int kgrp = lane >> 4;            // 0..3

    // A fragments: A[m][k] = Ww1[k][m], m = lane&15 (rows 8..15 zero)
    f16x8 aF0, aF1;
    {
        const int m = lane16;
        #pragma unroll
        for (int i = 0; i < 8; ++i) {
            const int k0 = kgrp*4 + (i & 3) + 16*(i >> 2);
            const int i0 = (m < 8) ? (k0*8 + m) : 0;
            const int i1 = (m < 8) ? ((k0 + 32)*8 + m) : 0;
            aF0[i] = (m < 8) ? (_Float16)Ww1[i0] : (_Float16)0.f;
            aF1[i] = (m < 8) ? (_Float16)Ww1[i1] : (_Float16)0.f;
        }
    }
    f32x4 cb;
    #pragma unroll
    for (int r = 0; r < 4; ++r) cb[r] = bww1[(kgrp*4 + r) & 7];

    float s3[4] = {0.f,0.f,0.f,0.f}, q3[4] = {0.f,0.f,0.f,0.f};
    const int nw = gridDim.x * 4;
    for (int pt = blockIdx.x*4 + wid; pt < NPTS; pt += nw) {
        const float xqc = xq[(size_t)pt*64 + lane];
        const int jreg = idx[pt*16 + lane16];
        const float pn0 = p[pt*3], pn1 = p[pt*3+1], pn2 = p[pt*3+2];
        const float d0 = p[jreg*3] - pn0, d1 = p[jreg*3+1] - pn1, d2 = p[jreg*3+2] - pn2;
        const float t0v = d0*w9[0] + d1*w9[3] + d2*w9[6] + bb[0];
        const float t1v = d0*w9[1] + d1*w9[4] + d2*w9[7] + bb[1];
        const float t2v = d0*w9[2] + d1*w9[5] + d2*w9[8] + bb[2];
        const float h0 = fmaxf(a1[0]*t0v + b1[0], 0.f);
        const float h1 = fmaxf(a1[1]*t1v + b1[1], 0.f);
        const float h2 = fmaxf(a1[2]*t2v + b1[2], 0.f);

        #pragma unroll
        for (int t = 0; t < 16; ++t) {
            const int jt = __builtin_amdgcn_readlane(jreg, t);
            const float g0 = rlF(h0, t), g1 = rlF(h1, t), g2 = rlF(h2, t);
            const float pr = fmaf(g0, wc0, fmaf(g1, wc1, fmaf(g2, wc2, bpc)));
            const float r = bf2f(xkb[(size_t)jt*64 + lane]) - xqc + pr;
            hl[wid][t][lane ^ ((t & 7) << 3)] = (_Float16)fmaxf(fmaf(a2c, r, b2c), 0.f);
        }

        const int t = lane16;
        const int key = (t & 7) << 3;
        union { f16x8 v; uint2 u[2]; } b0u, b1u;
        b0u.u[0] = *(const uint2*)&hl[wid][t][(kgrp*4)      ^ key];
        b0u.u[1] = *(const uint2*)&hl[wid][t][(kgrp*4 + 16) ^ key];
        b1u.u[0] = *(const uint2*)&hl[wid][t][(kgrp*4 + 32) ^ key];
        b1u.u[1] = *(const uint2*)&hl[wid][t][(kgrp*4 + 48) ^ key];

        f32x4 acc = __builtin_amdgcn_mfma_f32_16x16x32_f16(aF0, b0u.v, cb, 0, 0, 0);
        acc = __builtin_amdgcn_mfma_f32_16x16x32_f16(aF1, b1u.v, acc, 0, 0, 0);

        // D: col = lane&15 = t, row = kgrp*4 + r = j (lanes < 32 hold j = 0..7)
        if (lane < 32) {
            uint2 o;
            o.x = cvt_pk_bf16(acc[0], acc[1]);
            o.y = cvt_pk_bf16(acc[2], acc[3]);
            *(uint2*)&w1out[(size_t)pt*128 + lane16*8 + kgrp*4] = o;
            #pragma unroll
            for (int r = 0; r < 4; ++r) {
                s3[r] += acc[r];
                q3[r] = fmaf(acc[r], acc[r], q3[r]);
            }
        }
    }

    #pragma unroll
    for (int m = 8; m >= 1; m >>= 1) {
        #pragma unroll
        for (int r = 0; r < 4; ++r) {
            s3[r] += __shfl_xor(s3[r], m);
            q3[r] += __shfl_xor(q3[r], m);
        }
    }
    __shared__ float redS[4][8], redQ[4][8];
    if (lane == 0 || lane == 16) {
        const int jb = (lane >> 4) * 4;
        #pragma unroll
        for (int r = 0; r < 4; ++r) { redS[wid][jb+r] = s3[r]; redQ[wid][jb+r] = q3[r]; }
    }
    __syncthreads();
    if (tid < 8) {
        const float S = redS[0][tid]+redS[1][tid]+redS[2][tid]+redS[3][tid];
        const float Q = redQ[0][tid]+redQ[1][tid]+redQ[2][tid]+redQ[3][tid];
        part[(size_t)blockIdx.x*16 + tid]     = S;
        part[(size_t)blockIdx.x*16 + 8 + tid] = Q;
    }
}

// ---------------------------------------------------------------------------
// Kernel E: w2 = relu(bn3(w1)) @ Ww2 + bww2; softmax (no max-sub — inputs
// bounded by BN3+relu scale); weighted sum. No prefetch.
// ---------------------------------------------------------------------------
__global__ __launch_bounds__(256, 8) void out_kernel(
    const float* __restrict__ p, const int* __restrict__ idx,
    const unsigned short* __restrict__ xvb, const unsigned short* __restrict__ w1b,
    const float* __restrict__ Wp1, const float* __restrict__ bp1,
    const float* __restrict__ Wp2, const float* __restrict__ bp2,
    const float* __restrict__ Ww2, const float* __restrict__ bww2,
    const float* __restrict__ st, float* __restrict__ out)
{
    __shared__ float wl[4][16][8];
    const int tid = threadIdx.x, lane = tid & 63, wid = tid >> 6;
    const int j8 = lane & 7, t0 = lane >> 3;
    const int lane16 = lane & 15;

    float w9[9], bb[3], a1[3], b1[3];
    #pragma unroll
    for (int i = 0; i < 9; ++i) w9[i] = Wp1[i];
    #pragma unroll
    for (int i = 0; i < 3; ++i) { bb[i] = bp1[i]; a1[i] = st[S_BN1A+i]; b1[i] = st[S_BN1B+i]; }
    float ww2c[8];
    #pragma unroll
    for (int i = 0; i < 8; ++i) ww2c[i] = Ww2[i*8 + j8];
    const float a3j = st[S_BN3A + j8], b3j = st[S_BN3B + j8];
    const float bw2j = bww2[j8];
    const int c = lane;
    const float wc0 = Wp2[c], wc1 = Wp2[64+c], wc2 = Wp2[128+c], bpc = bp2[c];

    const int nw = gridDim.x * 4;
    for (int pt = blockIdx.x*4 + wid; pt < NPTS; pt += nw) {
        const int jreg = idx[pt*16 + lane16];
        const float pn0 = p[pt*3], pn1 = p[pt*3+1], pn2 = p[pt*3+2];
        const float d0 = p[jreg*3] - pn0, d1 = p[jreg*3+1] - pn1, d2 = p[jreg*3+2] - pn2;
        const float t1v = d0*w9[0] + d1*w9[3] + d2*w9[6] + bb[0];
        const float t2v = d0*w9[1] + d1*w9[4] + d2*w9[7] + bb[1];
        const float t3v = d0*w9[2] + d1*w9[5] + d2*w9[8] + bb[2];
        const float h0 = fmaxf(a1[0]*t1v + b1[0], 0.f);
        const float h1 = fmaxf(a1[1]*t2v + b1[1], 0.f);
        const float h2 = fmaxf(a1[2]*t3v + b1[2], 0.f);

        // phase 1: bn3 + 8x8 matmul within 8-lane groups; softmax over t
        const float val0 = bf2f(w1b[(size_t)pt*128 + lane]);
        const float val1 = bf2f(w1b[(size_t)pt*128 + 64 + lane]);
        const float r0 = fmaxf(a3j*val0 + b3j, 0.f);
        const float r1 = fmaxf(a3j*val1 + b3j, 0.f);
        float v0 = bw2j, v1 = bw2j;
        const int gbase = lane & 56;
        #pragma unroll
        for (int jj = 0; jj < 8; ++jj) {
            v0 += __shfl(r0, gbase + jj) * ww2c[jj];
            v1 += __shfl(r1, gbase + jj) * ww2c[jj];
        }
        float e0 = __expf(v0), e1 = __expf(v1);
        float ssum = e0 + e1;
        ssum += __shfl_xor(ssum, 8);
        ssum += __shfl_xor(ssum, 16);
        ssum += __shfl_xor(ssum, 32);
        const float inv = 1.0f / ssum;
        wl[wid][t0][j8]     = e0 * inv;
        wl[wid][t0 + 8][j8] = e1 * inv;

        // phase 2: weighted sum over neighbors, lane = output channel
        float acc = 0.f;
        #pragma unroll
        for (int t = 0; t < 16; ++t) {
            const int jt = __builtin_amdgcn_readlane(jreg, t);
            const float g0 = rlF(h0, t), g1 = rlF(h1, t), g2 = rlF(h2, t);
            const float pr = fmaf(g0, wc0, fmaf(g1, wc1, fmaf(g2, wc2, bpc)));
            const float wt = wl[wid][t][j8];
            acc = fmaf(bf2f(xvb[(size_t)jt*64 + c]) + pr, wt, acc);
        }
        out[(size_t)pt*64 + c] = acc;
    }
}

// ---------------------------------------------------------------------------
extern "C" void kernel_launch(void* const* d_in, const int* in_sizes, int n_in,
                              void* d_out, int out_size, void* d_ws, size_t ws_size,
                              hipStream_t stream)
{
    const float* p    = (const float*)d_in[0];
    const float* x    = (const float*)d_in[1];
    const int*   idx  = (const int*)d_in[3];
    const float* Wq   = (const float*)d_in[4];
    const float* bq   = (const float*)d_in[5];
    const float* Wk   = (const float*)d_in[6];
    const float* bk   = (const float*)d_in[7];
    const float* Wv   = (const float*)d_in[8];
    const float* bv   = (const float*)d_in[9];
    const float* Wp1  = (const float*)d_in[10];
    const float* bp1  = (const float*)d_in[11];
    const float* gp   = (const float*)d_in[12];
    const float* betap= (const float*)d_in[13];
    const float* Wp2  = (const float*)d_in[14];
    const float* bp2  = (const float*)d_in[15];
    const float* gw1  = (const float*)d_in[16];
    const float* bw1  = (const float*)d_in[17];
    const float* Ww1  = (const float*)d_in[18];
    const float* bww1 = (const float*)d_in[19];
    const float* gw2  = (const float*)d_in[20];
    const float* bw2  = (const float*)d_in[21];
    const float* Ww2  = (const float*)d_in[22];
    const float* bww2 = (const float*)d_in[23];

    float* out = (float*)d_out;
    float* ws  = (float*)d_ws;

    // workspace (float offsets): xq f32 [N*64] | xkb bf16 [N*32 fl] |
    // xvb bf16 [N*32] | w1b bf16 [N*64] | stats
    float*          xq  = ws;
    unsigned short* xkb = (unsigned short*)(ws + (size_t)NPTS*64);
    unsigned short* xvb = (unsigned short*)(ws + (size_t)NPTS*96);
    unsigned short* w1b = (unsigned short*)(ws + (size_t)NPTS*128);
    float*          st  = ws + (size_t)NPTS*192;

    qkv_bn1_kernel<<<NQKV + GRID_B, 256, 0, stream>>>(
        x, Wq, bq, Wk, bk, Wv, bv, xq, xkb, xvb,
        p, idx, Wp1, bp1, st + S_PARTB);
    bn_fin_kernel<<<3, 256, 0, stream>>>(st + S_PARTB, GRID_B, 8, 3, gp, betap,
                                         st + S_BN1A, st + S_BN1B);

    bn2_stats_kernel<<<GRID_C, 256, 0, stream>>>(p, idx, xq, xkb, Wp1, bp1, Wp2, bp2,
                                                 st, st + S_PARTC);
    bn_fin_kernel<<<64, 256, 0, stream>>>(st + S_PARTC, GRID_C, 128, 64, gw1, bw1,
                                          st + S_BN2A, st + S_BN2B);

    w1_kernel<<<GRID_D, 256, 0, stream>>>(p, idx, xq, xkb, Wp1, bp1, Wp2, bp2,
                                          Ww1, bww1, st, w1b, st + S_PARTD);
    bn_fin_kernel<<<8, 256, 0, stream>>>(st + S_PARTD, GRID_D, 16, 8, gw2, bw2,
                                         st + S_BN3A, st + S_BN3B);

    out_kernel<<<GRID_E, 256, 0, stream>>>(p, idx, xvb, w1b, Wp1, bp1, Wp2, bp2,
                                           Ww2, bww2, st, out);
}

// Round 12
// 228.193 us; speedup vs baseline: 1.1689x; 1.1077x over previous
//
#include <hip/hip_runtime.h>
#include <math.h>

#define NPTS 100000
#define NSAMP 16
#define NROWS (NPTS*NSAMP)
#define EPS 1e-5f

#define NQKV ((NPTS + 63)/64)
#define GRID_B 1024
#define GRID_C 2048
#define GRID_D 2048
#define GRID_E 2048

// stats layout (float offsets, relative to stats base `st`)
#define S_BN1A 0
#define S_BN1B 4
#define S_BN2A 8
#define S_BN2B 72
#define S_BN3A 136
#define S_BN3B 144
#define S_PARTB 160
#define S_PARTC (S_PARTB + GRID_B*8)
#define S_PARTD (S_PARTC + GRID_C*128)

typedef __attribute__((ext_vector_type(8))) _Float16 f16x8;
typedef __attribute__((ext_vector_type(4))) float f32x4;

__device__ __forceinline__ float bf2f(unsigned short u) {
    return __uint_as_float(((unsigned int)u) << 16);
}
// v_cvt_pk_bf16_f32: packs 2 f32 -> 2 bf16 (RNE) in one instruction
__device__ __forceinline__ unsigned int cvt_pk_bf16(float lo, float hi) {
    unsigned int r;
    asm("v_cvt_pk_bf16_f32 %0, %1, %2" : "=v"(r) : "v"(lo), "v"(hi));
    return r;
}
// uniform-lane broadcast via v_readlane (no LDS traffic)
__device__ __forceinline__ float rlF(float v, int t) {
    return __int_as_float(__builtin_amdgcn_readlane(__float_as_int(v), t));
}

// ---------------------------------------------------------------------------
// Kernel A (fused): blocks [0,NQKV) compute xqb/xkb/xvb (bf16);
// blocks [NQKV,+GRID_B) compute BN1 partial stats AND store the t-trunk
// tb[N,16,4] bf16 so bn2/w1/out never touch p again.
// ---------------------------------------------------------------------------
__global__ __launch_bounds__(256) void qkv_bn1_kernel(
    const float* __restrict__ x,
    const float* __restrict__ Wq, const float* __restrict__ bq,
    const float* __restrict__ Wk, const float* __restrict__ bk,
    const float* __restrict__ Wv, const float* __restrict__ bv,
    unsigned short* __restrict__ xqb, unsigned short* __restrict__ xkb,
    unsigned short* __restrict__ xvb,
    const float* __restrict__ p, const int* __restrict__ idx,
    const float* __restrict__ Wp1, const float* __restrict__ bp1,
    unsigned short* __restrict__ tb, float* __restrict__ part)
{
    __shared__ __align__(16) float xsh[64][68];
    __shared__ __align__(16) float wsh[64][64];
    __shared__ float red16[4][6];
    const int tid = threadIdx.x;

    if (blockIdx.x >= NQKV) {
        const int b = blockIdx.x - NQKV;
        float w9[9], bb[3];
        #pragma unroll
        for (int i = 0; i < 9; ++i) w9[i] = Wp1[i];
        #pragma unroll
        for (int i = 0; i < 3; ++i) bb[i] = bp1[i];

        float s0=0.f,s1=0.f,s2=0.f,q0=0.f,q1=0.f,q2=0.f;
        for (int row = b*256 + tid; row < NROWS; row += GRID_B*256) {
            const int n = row >> 4;
            const int j = idx[row];
            const float d0 = p[j*3+0] - p[n*3+0];
            const float d1 = p[j*3+1] - p[n*3+1];
            const float d2 = p[j*3+2] - p[n*3+2];
            const float t0 = d0*w9[0] + d1*w9[3] + d2*w9[6] + bb[0];
            const float t1 = d0*w9[1] + d1*w9[4] + d2*w9[7] + bb[1];
            const float t2 = d0*w9[2] + d1*w9[5] + d2*w9[8] + bb[2];
            uint2 o;
            o.x = cvt_pk_bf16(t0, t1);
            o.y = cvt_pk_bf16(t2, 0.f);
            *(uint2*)&tb[(size_t)row*4] = o;
            s0 += t0; s1 += t1; s2 += t2;
            q0 += t0*t0; q1 += t1*t1; q2 += t2*t2;
        }
        #pragma unroll
        for (int m = 32; m >= 1; m >>= 1) {
            s0 += __shfl_xor(s0, m); s1 += __shfl_xor(s1, m); s2 += __shfl_xor(s2, m);
            q0 += __shfl_xor(q0, m); q1 += __shfl_xor(q1, m); q2 += __shfl_xor(q2, m);
        }
        const int lane = tid & 63, wid = tid >> 6;
        if (lane == 0) {
            red16[wid][0]=s0; red16[wid][1]=s1; red16[wid][2]=s2;
            red16[wid][3]=q0; red16[wid][4]=q1; red16[wid][5]=q2;
        }
        __syncthreads();
        if (tid < 6)
            part[b*8 + tid] = red16[0][tid]+red16[1][tid]+red16[2][tid]+red16[3][tid];
        return;
    }

    const int r0 = blockIdx.x * 64;
    {
        const int row = tid >> 4, c4 = tid & 15;
        #pragma unroll
        for (int rr = 0; rr < 4; ++rr) {
            const int r = row + rr*16;
            const int gr = r0 + r;
            float4 v = (gr < NPTS) ? *(const float4*)&x[(size_t)gr*64 + c4*4]
                                   : make_float4(0.f, 0.f, 0.f, 0.f);
            *(float4*)&xsh[r][c4*4] = v;
        }
    }

    const int tr = tid >> 4, tc = tid & 15;

    for (int m = 0; m < 3; ++m) {
        const float* __restrict__ W  = (m == 0) ? Wq : (m == 1) ? Wk : Wv;
        const float* __restrict__ bs = (m == 0) ? bq : (m == 1) ? bk : bv;
        unsigned short* __restrict__ dst = (m == 0) ? xqb : (m == 1) ? xkb : xvb;

        __syncthreads();
        for (int l = tid; l < 1024; l += 256)
            *(float4*)&wsh[l >> 4][(l & 15)*4] = *(const float4*)&W[l*4];
        __syncthreads();

        float acc[4][4];
        {
            const float4 b4 = *(const float4*)&bs[tc*4];
            #pragma unroll
            for (int rr = 0; rr < 4; ++rr) {
                acc[rr][0] = b4.x; acc[rr][1] = b4.y;
                acc[rr][2] = b4.z; acc[rr][3] = b4.w;
            }
        }

        #pragma unroll 4
        for (int k4 = 0; k4 < 16; ++k4) {
            float4 xr[4];
            #pragma unroll
            for (int rr = 0; rr < 4; ++rr)
                xr[rr] = *(const float4*)&xsh[tr + 16*rr][k4*4];
            float4 wr[4];
            #pragma unroll
            for (int kk = 0; kk < 4; ++kk)
                wr[kk] = *(const float4*)&wsh[k4*4 + kk][tc*4];
            #pragma unroll
            for (int rr = 0; rr < 4; ++rr) {
                acc[rr][0] += xr[rr].x*wr[0].x + xr[rr].y*wr[1].x + xr[rr].z*wr[2].x + xr[rr].w*wr[3].x;
                acc[rr][1] += xr[rr].x*wr[0].y + xr[rr].y*wr[1].y + xr[rr].z*wr[2].y + xr[rr].w*wr[3].y;
                acc[rr][2] += xr[rr].x*wr[0].z + xr[rr].y*wr[1].z + xr[rr].z*wr[2].z + xr[rr].w*wr[3].z;
                acc[rr][3] += xr[rr].x*wr[0].w + xr[rr].y*wr[1].w + xr[rr].z*wr[2].w + xr[rr].w*wr[3].w;
            }
        }

        #pragma unroll
        for (int rr = 0; rr < 4; ++rr) {
            const int gr = r0 + tr + 16*rr;
            if (gr < NPTS) {
                uint2 o;
                o.x = cvt_pk_bf16(acc[rr][0], acc[rr][1]);
                o.y = cvt_pk_bf16(acc[rr][2], acc[rr][3]);
                *(uint2*)&dst[(size_t)gr*64 + tc*4] = o;
            }
        }
    }
}

// ---------------------------------------------------------------------------
// BN finalize
// ---------------------------------------------------------------------------
__global__ __launch_bounds__(256) void bn_fin_kernel(
    const float* __restrict__ part, int nblk, int stride, int nch,
    const float* __restrict__ g, const float* __restrict__ beta,
    float* __restrict__ aout, float* __restrict__ bout)
{
    const int c = blockIdx.x;
    const int tid = threadIdx.x;
    float s = 0.f, q = 0.f;
    for (int b = tid; b < nblk; b += 256) {
        s += part[(size_t)b*stride + c];
        q += part[(size_t)b*stride + nch + c];
    }
    #pragma unroll
    for (int m = 32; m >= 1; m >>= 1) { s += __shfl_xor(s, m); q += __shfl_xor(q, m); }
    __shared__ float rs[4], rq[4];
    if ((tid & 63) == 0) { rs[tid >> 6] = s; rq[tid >> 6] = q; }
    __syncthreads();
    if (tid == 0) {
        s = rs[0]+rs[1]+rs[2]+rs[3];
        q = rq[0]+rq[1]+rq[2]+rq[3];
        const float inv = 1.0f / (float)NROWS;
        const float mean = s * inv;
        const float var = fmaxf(q * inv - mean*mean, 0.f);
        const float a = g[c] * rsqrtf(var + EPS);
        aout[c] = a;
        bout[c] = beta[c] - a * mean;
    }
}

// ---------------------------------------------------------------------------
// Kernel C: BN2 stats. Trunk t0..t2 loaded from tb (one uint2 per lane16);
// h broadcast per-t via v_readlane. No p access at all.
// ---------------------------------------------------------------------------
__global__ __launch_bounds__(256, 8) void bn2_stats_kernel(
    const int* __restrict__ idx, const unsigned short* __restrict__ tb,
    const unsigned short* __restrict__ xqb, const unsigned short* __restrict__ xkb,
    const float* __restrict__ Wp2, const float* __restrict__ bp2,
    const float* __restrict__ st, float* __restrict__ part)
{
    const int tid = threadIdx.x, lane = tid & 63, wid = tid >> 6;
    float a1[3], b1[3];
    #pragma unroll
    for (int i = 0; i < 3; ++i) { a1[i] = st[S_BN1A+i]; b1[i] = st[S_BN1B+i]; }
    const float wc0 = Wp2[lane], wc1 = Wp2[64+lane], wc2 = Wp2[128+lane], bpc = bp2[lane];
    const int lane16 = lane & 15;

    float s = 0.f, q = 0.f;
    const int nw = gridDim.x * 4;
    for (int pt = blockIdx.x*4 + wid; pt < NPTS; pt += nw) {
        const float xqc = bf2f(xqb[(size_t)pt*64 + lane]);
        const int jreg = idx[pt*16 + lane16];
        const uint2 tv = *(const uint2*)&tb[(size_t)(pt*16 + lane16)*4];
        const float t0 = bf2f((unsigned short)tv.x);
        const float t1 = bf2f((unsigned short)(tv.x >> 16));
        const float t2 = bf2f((unsigned short)tv.y);
        const float h0 = fmaxf(a1[0]*t0 + b1[0], 0.f);
        const float h1 = fmaxf(a1[1]*t1 + b1[1], 0.f);
        const float h2 = fmaxf(a1[2]*t2 + b1[2], 0.f);

        #pragma unroll
        for (int t = 0; t < 16; ++t) {
            const int jt = __builtin_amdgcn_readlane(jreg, t);
            const float g0 = rlF(h0, t), g1 = rlF(h1, t), g2 = rlF(h2, t);
            const float pr = fmaf(g0, wc0, fmaf(g1, wc1, fmaf(g2, wc2, bpc)));
            const float r = bf2f(xkb[(size_t)jt*64 + lane]) - xqc + pr;
            s += r; q = fmaf(r, r, q);
        }
    }
    __shared__ float redS[4][64], redQ[4][64];
    redS[wid][lane] = s; redQ[wid][lane] = q;
    __syncthreads();
    if (tid < 64) {
        const float S = redS[0][tid]+redS[1][tid]+redS[2][tid]+redS[3][tid];
        const float Q = redQ[0][tid]+redQ[1][tid]+redQ[2][tid]+redQ[3][tid];
        part[(size_t)blockIdx.x*128 + tid] = S;
        part[(size_t)blockIdx.x*128 + 64 + tid] = Q;
    }
}

// ---------------------------------------------------------------------------
// Kernel D: w1 = relu(bn2(r_qk)) @ Ww1 + bww1 -> bf16 [NROWS,8] + BN3 stats.
// Trunk from tb; H staged f16 in XOR-swizzled LDS; 2x mfma_f32_16x16x32_f16.
// ---------------------------------------------------------------------------
__global__ __launch_bounds__(256, 8) void w1_kernel(
    const int* __restrict__ idx, const unsigned short* __restrict__ tb,
    const unsigned short* __restrict__ xqb, const unsigned short* __restrict__ xkb,
    const float* __restrict__ Wp2, const float* __restrict__ bp2,
    const float* __restrict__ Ww1, const float* __restrict__ bww1,
    const float* __restrict__ st, unsigned short* __restrict__ w1out,
    float* __restrict__ part)
{
    __shared__ __align__(16) _Float16 hl[4][16][64];   // f16 H rows, XOR-swizzled
    const int tid = threadIdx.x, lane = tid & 63, wid = tid >> 6;

    float a1[3], b1[3];
    #pragma unroll
    for (int i = 0; i < 3; ++i) { a1[i] = st[S_BN1A+i]; b1[i] = st[S_BN1B+i]; }

    const int c = lane;
    const float wc0 = Wp2[c], wc1 = Wp2[64+c], wc2 = Wp2[128+c], bpc = bp2[c];
    const float a2c = st[S_BN2A + c], b2c = st[S_BN2B + c];
    const int lane16 = lane & 15;
    const int kgrp = lane >> 4;            // 0..3

    // A fragments: A[m][k] = Ww1[k][m], m = lane&15 (rows 8..15 zero)
    f16x8 aF0, aF1;
    {
        const int m = lane16;
        #pragma unroll
        for (int i = 0; i < 8; ++i) {
            const int k0 = kgrp*4 + (i & 3) + 16*(i >> 2);
            const int i0 = (m < 8) ? (k0*8 + m) : 0;
            const int i1 = (m < 8) ? ((k0 + 32)*8 + m) : 0;
            aF0[i] = (m < 8) ? (_Float16)Ww1[i0] : (_Float16)0.f;
            aF1[i] = (m < 8) ? (_Float16)Ww1[i1] : (_Float16)0.f;
        }
    }
    f32x4 cb;
    #pragma unroll
    for (int r = 0; r < 4; ++r) cb[r] = bww1[(kgrp*4 + r) & 7];

    float s3[4] = {0.f,0.f,0.f,0.f}, q3[4] = {0.f,0.f,0.f,0.f};
    const int nw = gridDim.x * 4;
    for (int pt = blockIdx.x*4 + wid; pt < NPTS; pt += nw) {
        const float xqc = bf2f(xqb[(size_t)pt*64 + lane]);
        const int jreg = idx[pt*16 + lane16];
        const uint2 tv = *(const uint2*)&tb[(size_t)(pt*16 + lane16)*4];
        const float t0v = bf2f((unsigned short)tv.x);
        const float t1v = bf2f((unsigned short)(tv.x >> 16));
        const float t2v = bf2f((unsigned short)tv.y);
        const float h0 = fmaxf(a1[0]*t0v + b1[0], 0.f);
        const float h1 = fmaxf(a1[1]*t1v + b1[1], 0.f);
        const float h2 = fmaxf(a1[2]*t2v + b1[2], 0.f);

        #pragma unroll
        for (int t = 0; t < 16; ++t) {
            const int jt = __builtin_amdgcn_readlane(jreg, t);
            const float g0 = rlF(h0, t), g1 = rlF(h1, t), g2 = rlF(h2, t);
            const float pr = fmaf(g0, wc0, fmaf(g1, wc1, fmaf(g2, wc2, bpc)));
            const float r = bf2f(xkb[(size_t)jt*64 + lane]) - xqc + pr;
            hl[wid][t][lane ^ ((t & 7) << 3)] = (_Float16)fmaxf(fmaf(a2c, r, b2c), 0.f);
        }

        const int t = lane16;
        const int key = (t & 7) << 3;
        union { f16x8 v; uint2 u[2]; } b0u, b1u;
        b0u.u[0] = *(const uint2*)&hl[wid][t][(kgrp*4)      ^ key];
        b0u.u[1] = *(const uint2*)&hl[wid][t][(kgrp*4 + 16) ^ key];
        b1u.u[0] = *(const uint2*)&hl[wid][t][(kgrp*4 + 32) ^ key];
        b1u.u[1] = *(const uint2*)&hl[wid][t][(kgrp*4 + 48) ^ key];

        f32x4 acc = __builtin_amdgcn_mfma_f32_16x16x32_f16(aF0, b0u.v, cb, 0, 0, 0);
        acc = __builtin_amdgcn_mfma_f32_16x16x32_f16(aF1, b1u.v, acc, 0, 0, 0);

        // D: col = lane&15 = t, row = kgrp*4 + r = j (lanes < 32 hold j = 0..7)
        if (lane < 32) {
            uint2 o;
            o.x = cvt_pk_bf16(acc[0], acc[1]);
            o.y = cvt_pk_bf16(acc[2], acc[3]);
            *(uint2*)&w1out[(size_t)pt*128 + lane16*8 + kgrp*4] = o;
            #pragma unroll
            for (int r = 0; r < 4; ++r) {
                s3[r] += acc[r];
                q3[r] = fmaf(acc[r], acc[r], q3[r]);
            }
        }
    }

    #pragma unroll
    for (int m = 8; m >= 1; m >>= 1) {
        #pragma unroll
        for (int r = 0; r < 4; ++r) {
            s3[r] += __shfl_xor(s3[r], m);
            q3[r] += __shfl_xor(q3[r], m);
        }
    }
    __shared__ float redS[4][8], redQ[4][8];
    if (lane == 0 || lane == 16) {
        const int jb = (lane >> 4) * 4;
        #pragma unroll
        for (int r = 0; r < 4; ++r) { redS[wid][jb+r] = s3[r]; redQ[wid][jb+r] = q3[r]; }
    }
    __syncthreads();
    if (tid < 8) {
        const float S = redS[0][tid]+redS[1][tid]+redS[2][tid]+redS[3][tid];
        const float Q = redQ[0][tid]+redQ[1][tid]+redQ[2][tid]+redQ[3][tid];
        part[(size_t)blockIdx.x*16 + tid]     = S;
        part[(size_t)blockIdx.x*16 + 8 + tid] = Q;
    }
}

// ---------------------------------------------------------------------------
// Kernel E: w2 = relu(bn3(w1)) @ Ww2 + bww2; softmax (no max-sub); weighted
// sum. Trunk from tb; no p access.
// ---------------------------------------------------------------------------
__global__ __launch_bounds__(256, 8) void out_kernel(
    const int* __restrict__ idx, const unsigned short* __restrict__ tb,
    const unsigned short* __restrict__ xvb, const unsigned short* __restrict__ w1b,
    const float* __restrict__ Wp2, const float* __restrict__ bp2,
    const float* __restrict__ Ww2, const float* __restrict__ bww2,
    const float* __restrict__ st, float* __restrict__ out)
{
    __shared__ float wl[4][16][8];
    const int tid = threadIdx.x, lane = tid & 63, wid = tid >> 6;
    const int j8 = lane & 7, t0 = lane >> 3;
    const int lane16 = lane & 15;

    float a1[3], b1[3];
    #pragma unroll
    for (int i = 0; i < 3; ++i) { a1[i] = st[S_BN1A+i]; b1[i] = st[S_BN1B+i]; }
    float ww2c[8];
    #pragma unroll
    for (int i = 0; i < 8; ++i) ww2c[i] = Ww2[i*8 + j8];
    const float a3j = st[S_BN3A + j8], b3j = st[S_BN3B + j8];
    const float bw2j = bww2[j8];
    const int c = lane;
    const float wc0 = Wp2[c], wc1 = Wp2[64+c], wc2 = Wp2[128+c], bpc = bp2[c];

    const int nw = gridDim.x * 4;
    for (int pt = blockIdx.x*4 + wid; pt < NPTS; pt += nw) {
        const int jreg = idx[pt*16 + lane16];
        const uint2 tv = *(const uint2*)&tb[(size_t)(pt*16 + lane16)*4];
        const float t1v = bf2f((unsigned short)tv.x);
        const float t2v = bf2f((unsigned short)(tv.x >> 16));
        const float t3v = bf2f((unsigned short)tv.y);
        const float h0 = fmaxf(a1[0]*t1v + b1[0], 0.f);
        const float h1 = fmaxf(a1[1]*t2v + b1[1], 0.f);
        const float h2 = fmaxf(a1[2]*t3v + b1[2], 0.f);

        // phase 1: bn3 + 8x8 matmul within 8-lane groups; softmax over t
        const float val0 = bf2f(w1b[(size_t)pt*128 + lane]);
        const float val1 = bf2f(w1b[(size_t)pt*128 + 64 + lane]);
        const float r0 = fmaxf(a3j*val0 + b3j, 0.f);
        const float r1 = fmaxf(a3j*val1 + b3j, 0.f);
        float v0 = bw2j, v1 = bw2j;
        const int gbase = lane & 56;
        #pragma unroll
        for (int jj = 0; jj < 8; ++jj) {
            v0 += __shfl(r0, gbase + jj) * ww2c[jj];
            v1 += __shfl(r1, gbase + jj) * ww2c[jj];
        }
        float e0 = __expf(v0), e1 = __expf(v1);
        float ssum = e0 + e1;
        ssum += __shfl_xor(ssum, 8);
        ssum += __shfl_xor(ssum, 16);
        ssum += __shfl_xor(ssum, 32);
        const float inv = 1.0f / ssum;
        wl[wid][t0][j8]     = e0 * inv;
        wl[wid][t0 + 8][j8] = e1 * inv;

        // phase 2: weighted sum over neighbors, lane = output channel
        float acc = 0.f;
        #pragma unroll
        for (int t = 0; t < 16; ++t) {
            const int jt = __builtin_amdgcn_readlane(jreg, t);
            const float g0 = rlF(h0, t), g1 = rlF(h1, t), g2 = rlF(h2, t);
            const float pr = fmaf(g0, wc0, fmaf(g1, wc1, fmaf(g2, wc2, bpc)));
            const float wt = wl[wid][t][j8];
            acc = fmaf(bf2f(xvb[(size_t)jt*64 + c]) + pr, wt, acc);
        }
        out[(size_t)pt*64 + c] = acc;
    }
}

// ---------------------------------------------------------------------------
extern "C" void kernel_launch(void* const* d_in, const int* in_sizes, int n_in,
                              void* d_out, int out_size, void* d_ws, size_t ws_size,
                              hipStream_t stream)
{
    const float* p    = (const float*)d_in[0];
    const float* x    = (const float*)d_in[1];
    const int*   idx  = (const int*)d_in[3];
    const float* Wq   = (const float*)d_in[4];
    const float* bq   = (const float*)d_in[5];
    const float* Wk   = (const float*)d_in[6];
    const float* bk   = (const float*)d_in[7];
    const float* Wv   = (const float*)d_in[8];
    const float* bv   = (const float*)d_in[9];
    const float* Wp1  = (const float*)d_in[10];
    const float* bp1  = (const float*)d_in[11];
    const float* gp   = (const float*)d_in[12];
    const float* betap= (const float*)d_in[13];
    const float* Wp2  = (const float*)d_in[14];
    const float* bp2  = (const float*)d_in[15];
    const float* gw1  = (const float*)d_in[16];
    const float* bw1  = (const float*)d_in[17];
    const float* Ww1  = (const float*)d_in[18];
    const float* bww1 = (const float*)d_in[19];
    const float* gw2  = (const float*)d_in[20];
    const float* bw2  = (const float*)d_in[21];
    const float* Ww2  = (const float*)d_in[22];
    const float* bww2 = (const float*)d_in[23];

    float* out = (float*)d_out;
    float* ws  = (float*)d_ws;

    // workspace (float offsets): xqb bf16 [N*32 fl] | xkb [N*32] | xvb [N*32]
    // | w1b bf16 [N*64] | tb bf16 [N*16*4 ush = N*32 fl] | stats
    unsigned short* xqb = (unsigned short*)ws;
    unsigned short* xkb = (unsigned short*)(ws + (size_t)NPTS*32);
    unsigned short* xvb = (unsigned short*)(ws + (size_t)NPTS*64);
    unsigned short* w1b = (unsigned short*)(ws + (size_t)NPTS*96);
    unsigned short* tb  = (unsigned short*)(ws + (size_t)NPTS*160);
    float*          st  = ws + (size_t)NPTS*192;

    qkv_bn1_kernel<<<NQKV + GRID_B, 256, 0, stream>>>(
        x, Wq, bq, Wk, bk, Wv, bv, xqb, xkb, xvb,
        p, idx, Wp1, bp1, tb, st + S_PARTB);
    bn_fin_kernel<<<3, 256, 0, stream>>>(st + S_PARTB, GRID_B, 8, 3, gp, betap,
                                         st + S_BN1A, st + S_BN1B);

    bn2_stats_kernel<<<GRID_C, 256, 0, stream>>>(idx, tb, xqb, xkb, Wp2, bp2,
                                                 st, st + S_PARTC);
    bn_fin_kernel<<<64, 256, 0, stream>>>(st + S_PARTC, GRID_C, 128, 64, gw1, bw1,
                                          st + S_BN2A, st + S_BN2B);

    w1_kernel<<<GRID_D, 256, 0, stream>>>(idx, tb, xqb, xkb, Wp2, bp2,
                                          Ww1, bww1, st, w1b, st + S_PARTD);
    bn_fin_kernel<<<8, 256, 0, stream>>>(st + S_PARTD, GRID_D, 16, 8, gw2, bw2,
                                         st + S_BN3A, st + S_BN3B);

    out_kernel<<<GRID_E, 256, 0, stream>>>(idx, tb, xvb, w1b, Wp2, bp2,
                                           Ww2, bww2, st, out);
}